// Round 5
// baseline (443.836 us; speedup 1.0000x reference)
//
#include <hip/hip_runtime.h>
#include <hip/hip_bf16.h>

#define K_DIM 4096
#define NITER (K_DIM / 256)   // 16 float4 chunks per row per lane

typedef float f32x4 __attribute__((ext_vector_type(4)));

// One wave (64 lanes) computes one output row: two dot-products of length
// 4096. Lanes stride over K with float4 loads (16 B/lane -> 1 KiB/instr,
// fully coalesced).
//
// NO LDS: each lane's W fragment (16 float4 per column = 128 VGPR total) is
// loop-invariant across all its rows -> hoisted into registers once at kernel
// start (32 global float4 loads, L2-served; W is only 32 KB and every block
// reads it). This removes the 32KB/block LDS residency cap, the per-iteration
// ds_read_b128 pair, the __syncthreads, and all W re-staging.
//
// Journal: R1 201.7us / R4 (same source) 367us -> session noise ~1.8x; judge
// vs in-session fill-dispatch anchor (~670us per 4.3GB fill = 6.4 TB/s).
__global__ void moe_rowdot_kernel(
    const float* __restrict__ A,   // [BATCH][K_DIM]
    const float* __restrict__ W,   // [K_DIM][2] row-major
    float* __restrict__ out,       // [BATCH][2]
    int batch) {

    const int lane          = threadIdx.x & 63;
    const int waveInBlock   = threadIdx.x >> 6;
    const int wavesPerBlock = blockDim.x >> 6;
    const int globalWave    = blockIdx.x * wavesPerBlock + waveInBlock;
    const int numWaves      = gridDim.x * wavesPerBlock;

    // Hoist this lane's W fragment into registers.
    // For float4-chunk idx = it*64+lane (k = 4*idx..4*idx+3), the row-major
    // [K][2] layout interleaves columns: load two float4 (8 floats) and
    // de-interleave into wr0 (col 0) / wr1 (col 1).
    f32x4 wr0[NITER], wr1[NITER];
    {
        const f32x4* Wv = reinterpret_cast<const f32x4*>(W);
        #pragma unroll
        for (int it = 0; it < NITER; ++it) {
            const int idx = it * 64 + lane;
            f32x4 p = Wv[2 * idx];       // w0[k],w1[k],w0[k+1],w1[k+1]
            f32x4 q = Wv[2 * idx + 1];   // k+2, k+3
            wr0[it] = (f32x4){p.x, p.z, q.x, q.z};
            wr1[it] = (f32x4){p.y, p.w, q.y, q.w};
        }
    }

    for (int row = globalWave; row < batch; row += numWaves) {
        const f32x4* arow =
            reinterpret_cast<const f32x4*>(A + (size_t)row * K_DIM);
        float acc0 = 0.f, acc1 = 0.f;
        #pragma unroll
        for (int it = 0; it < NITER; ++it) {
            f32x4 a = arow[it * 64 + lane];
            acc0 += a.x * wr0[it].x + a.y * wr0[it].y
                  + a.z * wr0[it].z + a.w * wr0[it].w;
            acc1 += a.x * wr1[it].x + a.y * wr1[it].y
                  + a.z * wr1[it].z + a.w * wr1[it].w;
        }
        // Wave-wide reduction (64 lanes).
        #pragma unroll
        for (int off = 32; off > 0; off >>= 1) {
            acc0 += __shfl_xor(acc0, off);
            acc1 += __shfl_xor(acc1, off);
        }
        if (lane == 0) {
            reinterpret_cast<float2*>(out)[row] = make_float2(acc0, acc1);
        }
    }
}

extern "C" void kernel_launch(void* const* d_in, const int* in_sizes, int n_in,
                              void* d_out, int out_size, void* d_ws, size_t ws_size,
                              hipStream_t stream) {
    const float* A = (const float*)d_in[0];   // router_weights [65536][4096]
    const float* W = (const float*)d_in[1];   // W_values [4096][2]
    float* out = (float*)d_out;               // [65536][2]

    const int batch = in_sizes[0] / K_DIM;    // 65536

    // 2048 blocks x 256 threads = 8192 waves; 8 rows per wave grid-stride.
    // VGPR-bound residency ~2 blocks/CU -> 4 exact phases of 512 blocks.
    const int blocks = 2048;
    moe_rowdot_kernel<<<blocks, 256, 0, stream>>>(A, W, out, batch);
}

// Round 6
// 367.860 us; speedup vs baseline: 1.2065x; 1.2065x over previous
//
#include <hip/hip_runtime.h>
#include <hip/hip_bf16.h>

#define K_DIM 4096

// FINAL: exact R1 structure (best clean measurement: 201.7 us = 5.33 TB/s
// effective read, 84% of this chip's demonstrated 6.4 TB/s fill BW).
//
// One wave (64 lanes) computes one output row: two dot-products of length
// 4096. Lanes stride over K with float4 loads (16 B/lane -> 1 KiB per
// instruction, fully coalesced). W (4096x2, 32 KB) staged per-block into
// LDS, column-split so LDS reads are contiguous b128 (conflict-free).
// 2048 blocks x 4 waves = 8192 waves -> exactly 8 rows/wave, zero imbalance.
//
// Session journal (why nothing else is here):
//   R1 201.7us  this source.
//   R2 335.8us  __launch_bounds__(256,4)+1024 blocks     -> reverted.
//   R3 341.9us  nontemporal A loads                       -> reverted.
//   R4 367.2us  EXACT R1 SOURCE re-bench                  -> environment!
//   R5 443.8us  W-in-registers, no LDS                    -> reverted.
// dur_us rose monotonically across rounds regardless of source while fill
// dispatches held 6.4-6.6 TB/s constant => session-level degradation
// (clock/co-tenant) dominates; cross-round deltas are not causal. This
// kernel is HBM-read-bound: 1.074 GB must-read, roofline ~175 us @ 6.3 TB/s.
__global__ void moe_rowdot_kernel(
    const float* __restrict__ A,   // [BATCH][K_DIM]
    const float* __restrict__ W,   // [K_DIM][2]
    float* __restrict__ out,       // [BATCH][2]
    int batch) {

    __shared__ float w0[K_DIM];
    __shared__ float w1[K_DIM];

    // Stage W into LDS (column-split). W is row-major [K][2] -> float2 per k.
    for (int i = threadIdx.x; i < K_DIM; i += blockDim.x) {
        float2 wv = reinterpret_cast<const float2*>(W)[i];
        w0[i] = wv.x;
        w1[i] = wv.y;
    }
    __syncthreads();

    const int lane          = threadIdx.x & 63;
    const int waveInBlock   = threadIdx.x >> 6;
    const int wavesPerBlock = blockDim.x >> 6;
    const int globalWave    = blockIdx.x * wavesPerBlock + waveInBlock;
    const int numWaves      = gridDim.x * wavesPerBlock;

    const float4* w0v = reinterpret_cast<const float4*>(w0);
    const float4* w1v = reinterpret_cast<const float4*>(w1);

    for (int row = globalWave; row < batch; row += numWaves) {
        const float4* arow =
            reinterpret_cast<const float4*>(A + (size_t)row * K_DIM);
        float acc0 = 0.f, acc1 = 0.f;
        // K_DIM / (64 lanes * 4 floats) = 16 iterations
        #pragma unroll
        for (int it = 0; it < K_DIM / 256; ++it) {
            const int idx = it * 64 + lane;      // float4 index
            float4 a  = arow[idx];
            float4 b0 = w0v[idx];
            float4 b1 = w1v[idx];
            acc0 += a.x * b0.x + a.y * b0.y + a.z * b0.z + a.w * b0.w;
            acc1 += a.x * b1.x + a.y * b1.y + a.z * b1.z + a.w * b1.w;
        }
        // Wave-wide reduction (64 lanes).
        #pragma unroll
        for (int off = 32; off > 0; off >>= 1) {
            acc0 += __shfl_xor(acc0, off);
            acc1 += __shfl_xor(acc1, off);
        }
        if (lane == 0) {
            reinterpret_cast<float2*>(out)[row] = make_float2(acc0, acc1);
        }
    }
}

extern "C" void kernel_launch(void* const* d_in, const int* in_sizes, int n_in,
                              void* d_out, int out_size, void* d_ws, size_t ws_size,
                              hipStream_t stream) {
    const float* A = (const float*)d_in[0];   // router_weights [65536][4096]
    const float* W = (const float*)d_in[1];   // W_values [4096][2]
    float* out = (float*)d_out;               // [65536][2]

    const int batch = in_sizes[0] / K_DIM;    // 65536

    // 2048 blocks x 256 threads = 8192 waves; 8 rows per wave grid-stride.
    const int blocks = 2048;
    moe_rowdot_kernel<<<blocks, 256, 0, stream>>>(A, W, out, batch);
}

// Round 7
// 184.239 us; speedup vs baseline: 2.4090x; 1.9966x over previous
//
#include <hip/hip_runtime.h>
#include <hip/hip_bf16.h>

#define K_DIM 4096

// R7: R1 structure with 512-thread blocks for FULL occupancy.
// Occupancy math: 32 KB LDS/block. 256-thr blocks -> 5 blocks/CU x 4 waves
// = 20/32 waves. 512-thr blocks -> 4 blocks/CU x 8 waves = 32/32 waves
// (LDS 128 KB <= 160 KB). +60% latency hiding, same coalescing, same
// zero-imbalance 8 rows/wave (1024 blocks x 8 waves = 8192 waves).
//
// Session journal:
//   R1 201.7us (R1 src)            -- fast session (outlier node).
//   R2 335.8us lb(256,4)+1024blk   -- slow regime: actually a WIN vs 367.
//   R3 341.9us nontemporal A       -- slow regime: also a win vs 367.
//   R4 367.2us EXACT R1 src        -- slow regime anchor.
//   R5 443.8us W-in-regs, no LDS   -- genuine loss (occupancy collapse).
//   R6 367.9us EXACT R1 src        -- reproduces R4 to 0.2% => measurements
//      are stable now; R1 was the anomaly. Slow regime = read-latency
//      inflation (fills hold 6.4 TB/s; posted writes unaffected) => raise
//      occupancy.
__global__ __launch_bounds__(512) void moe_rowdot_kernel(
    const float* __restrict__ A,   // [BATCH][K_DIM]
    const float* __restrict__ W,   // [K_DIM][2]
    float* __restrict__ out,       // [BATCH][2]
    int batch) {

    __shared__ float w0[K_DIM];
    __shared__ float w1[K_DIM];

    // Stage W into LDS (column-split). W is row-major [K][2] -> float2 per k.
    for (int i = threadIdx.x; i < K_DIM; i += blockDim.x) {
        float2 wv = reinterpret_cast<const float2*>(W)[i];
        w0[i] = wv.x;
        w1[i] = wv.y;
    }
    __syncthreads();

    const int lane          = threadIdx.x & 63;
    const int waveInBlock   = threadIdx.x >> 6;
    const int wavesPerBlock = blockDim.x >> 6;
    const int globalWave    = blockIdx.x * wavesPerBlock + waveInBlock;
    const int numWaves      = gridDim.x * wavesPerBlock;

    const float4* w0v = reinterpret_cast<const float4*>(w0);
    const float4* w1v = reinterpret_cast<const float4*>(w1);

    for (int row = globalWave; row < batch; row += numWaves) {
        const float4* arow =
            reinterpret_cast<const float4*>(A + (size_t)row * K_DIM);
        float acc0 = 0.f, acc1 = 0.f;
        // K_DIM / (64 lanes * 4 floats) = 16 iterations
        #pragma unroll
        for (int it = 0; it < K_DIM / 256; ++it) {
            const int idx = it * 64 + lane;      // float4 index
            float4 a  = arow[idx];
            float4 b0 = w0v[idx];
            float4 b1 = w1v[idx];
            acc0 += a.x * b0.x + a.y * b0.y + a.z * b0.z + a.w * b0.w;
            acc1 += a.x * b1.x + a.y * b1.y + a.z * b1.z + a.w * b1.w;
        }
        // Wave-wide reduction (64 lanes).
        #pragma unroll
        for (int off = 32; off > 0; off >>= 1) {
            acc0 += __shfl_xor(acc0, off);
            acc1 += __shfl_xor(acc1, off);
        }
        if (lane == 0) {
            reinterpret_cast<float2*>(out)[row] = make_float2(acc0, acc1);
        }
    }
}

extern "C" void kernel_launch(void* const* d_in, const int* in_sizes, int n_in,
                              void* d_out, int out_size, void* d_ws, size_t ws_size,
                              hipStream_t stream) {
    const float* A = (const float*)d_in[0];   // router_weights [65536][4096]
    const float* W = (const float*)d_in[1];   // W_values [4096][2]
    float* out = (float*)d_out;               // [65536][2]

    const int batch = in_sizes[0] / K_DIM;    // 65536

    // 1024 blocks x 512 threads = 8192 waves; 8 rows per wave, zero tail.
    // 4 blocks/CU -> 32 waves/CU (full occupancy).
    const int blocks = 1024;
    moe_rowdot_kernel<<<blocks, 512, 0, stream>>>(A, W, out, batch);
}